// Round 1
// baseline (137.959 us; speedup 1.0000x reference)
//
#include <hip/hip_runtime.h>
#include <hip/hip_bf16.h>
#include <stdint.h>

// Problem: out[i][j] = dot(x[i], y[j]) / max(|x[i]|*|y[j]|, 1e-8) / 0.05
// x: [4096,1024] f32, y: [4096,1024] f32, out: [4096,4096] f32
#define MDIM 4096
#define NDIM 4096
#define KDIM 1024
#define TEMP_INV 20.0f

typedef __bf16 bf16x8 __attribute__((ext_vector_type(8)));
typedef float f32x4 __attribute__((ext_vector_type(4)));

typedef __attribute__((address_space(3))) void lds_void_t;
typedef __attribute__((address_space(1))) void glb_void_t;

__device__ __forceinline__ void async_copy16(const void* g, void* l) {
    // width=16 global->LDS DMA. LDS dest semantics: wave-uniform base + lane*16,
    // so per-thread lds ptr MUST be base + tid*16 within contiguous layout.
    __builtin_amdgcn_global_load_lds((glb_void_t*)(uintptr_t)g,
                                     (lds_void_t*)(uint32_t)(uintptr_t)l,
                                     16, 0, 0);
}

__device__ __forceinline__ unsigned short f32_to_bf16_rne(float f) {
    union { float f; uint32_t u; } v;
    v.f = f;
    uint32_t u = v.u;
    uint32_t r = (u + 0x7FFFu + ((u >> 16) & 1u)) >> 16;
    return (unsigned short)r;
}

// One block per row (grid.y selects x vs y): convert row to bf16, store 1/norm.
__global__ __launch_bounds__(256) void prep_kernel(const float* __restrict__ x,
                                                   const float* __restrict__ y,
                                                   unsigned short* __restrict__ xb,
                                                   unsigned short* __restrict__ yb,
                                                   float* __restrict__ rnx,
                                                   float* __restrict__ rny) {
    const int row = blockIdx.x;
    const float* src = (blockIdx.y == 0) ? x : y;
    unsigned short* dst = (blockIdx.y == 0) ? xb : yb;
    float* rn = (blockIdx.y == 0) ? rnx : rny;
    const int t = threadIdx.x;

    float4 v = ((const float4*)(src + (size_t)row * KDIM))[t];

    ushort4 b;
    b.x = f32_to_bf16_rne(v.x);
    b.y = f32_to_bf16_rne(v.y);
    b.z = f32_to_bf16_rne(v.z);
    b.w = f32_to_bf16_rne(v.w);
    ((ushort4*)(dst + (size_t)row * KDIM))[t] = b;

    float ss = v.x * v.x + v.y * v.y + v.z * v.z + v.w * v.w;
#pragma unroll
    for (int off = 32; off > 0; off >>= 1) ss += __shfl_down(ss, off);

    __shared__ float red[4];
    if ((t & 63) == 0) red[t >> 6] = ss;
    __syncthreads();
    if (t == 0) {
        float s = red[0] + red[1] + red[2] + red[3];
        float norm = sqrtf(s);
        rn[row] = 1.0f / fmaxf(norm, 1e-8f);
    }
}

// 128x128 tile, BK=32, 4 waves each computing a 64x64 subtile as 4x4 MFMA tiles.
__global__ __launch_bounds__(256) void gemm_cos_kernel(const unsigned short* __restrict__ Xb,
                                                       const unsigned short* __restrict__ Yb,
                                                       const float* __restrict__ rnx,
                                                       const float* __restrict__ rny,
                                                       float* __restrict__ out) {
    __shared__ __bf16 As[128 * 32];  // 8 KB
    __shared__ __bf16 Bs[128 * 32];  // 8 KB

    const int tid = threadIdx.x;
    const int bm = blockIdx.y;
    const int bn = blockIdx.x;

    // Staging: thread t covers 16B = 8 bf16 at (row=t>>2, col8=t&3); two calls
    // per matrix cover rows 0..63 and 64..127. LDS byte offset = t*16 (+4096).
    const unsigned short* gA = Xb + (size_t)(bm * 128 + (tid >> 2)) * KDIM + (tid & 3) * 8;
    const unsigned short* gB = Yb + (size_t)(bn * 128 + (tid >> 2)) * KDIM + (tid & 3) * 8;
    __bf16* lA = As + tid * 8;
    __bf16* lB = Bs + tid * 8;

    const int lane = tid & 63;
    const int wv = tid >> 6;
    const int wr = (wv >> 1) * 64;  // wave row origin in tile
    const int wc = (wv & 1) * 64;   // wave col origin in tile
    const int m16 = lane & 15;
    const int q = lane >> 4;

    // A-operand layout: A[m=lane&15][k=q*8+j]; B mirrors with n=lane&15.
    const __bf16* pa = As + (wr + m16) * 32 + q * 8;
    const __bf16* pb = Bs + (wc + m16) * 32 + q * 8;

    f32x4 acc[4][4] = {};

    for (int kt = 0; kt < KDIM; kt += 32) {
        __syncthreads();  // previous iteration's LDS reads complete
        async_copy16(gA + kt, lA);
        async_copy16(gA + kt + 64 * KDIM, lA + 64 * 32);
        async_copy16(gB + kt, lB);
        async_copy16(gB + kt + 64 * KDIM, lB + 64 * 32);
        __syncthreads();  // staged data visible (vmcnt drained before barrier)

        bf16x8 af[4], bfr[4];
#pragma unroll
        for (int i = 0; i < 4; ++i) af[i] = *(const bf16x8*)(pa + i * 16 * 32);
#pragma unroll
        for (int j = 0; j < 4; ++j) bfr[j] = *(const bf16x8*)(pb + j * 16 * 32);
#pragma unroll
        for (int i = 0; i < 4; ++i)
#pragma unroll
            for (int j = 0; j < 4; ++j)
                acc[i][j] = __builtin_amdgcn_mfma_f32_16x16x32_bf16(af[i], bfr[j], acc[i][j], 0, 0, 0);
    }

    // C/D layout (measured m89/m91): col = lane&15, row = q*4 + reg.
    const int gr0 = bm * 128 + wr + q * 4;
    const int gc0 = bn * 128 + wc + m16;
#pragma unroll
    for (int j = 0; j < 4; ++j) {
        const int gc = gc0 + j * 16;
        const float sy = rny[gc] * TEMP_INV;
#pragma unroll
        for (int i = 0; i < 4; ++i) {
            const int gr = gr0 + i * 16;
#pragma unroll
            for (int r = 0; r < 4; ++r) {
                out[(size_t)(gr + r) * NDIM + gc] = acc[i][j][r] * rnx[gr + r] * sy;
            }
        }
    }
}

extern "C" void kernel_launch(void* const* d_in, const int* in_sizes, int n_in,
                              void* d_out, int out_size, void* d_ws, size_t ws_size,
                              hipStream_t stream) {
    const float* x = (const float*)d_in[0];
    const float* y = (const float*)d_in[1];
    float* out = (float*)d_out;

    char* ws = (char*)d_ws;
    unsigned short* Xb = (unsigned short*)ws;                                   // 8 MB
    unsigned short* Yb = (unsigned short*)(ws + (size_t)MDIM * KDIM * 2);       // 8 MB
    float* rnx = (float*)(ws + (size_t)(MDIM + NDIM) * KDIM * 2);               // 16 KB
    float* rny = rnx + MDIM;                                                    // 16 KB

    prep_kernel<<<dim3(MDIM, 2), 256, 0, stream>>>(x, y, Xb, Yb, rnx, rny);
    gemm_cos_kernel<<<dim3(NDIM / 128, MDIM / 128), 256, 0, stream>>>(Xb, Yb, rnx, rny, out);
}

// Round 2
// 127.368 us; speedup vs baseline: 1.0832x; 1.0832x over previous
//
#include <hip/hip_runtime.h>
#include <hip/hip_bf16.h>
#include <stdint.h>

// out[i][j] = dot(x[i], y[j]) / max(|x[i]|*|y[j]|, 1e-8) / 0.05
// x,y: [4096,1024] f32; out: [4096,4096] f32
#define MDIM 4096
#define NDIM 4096
#define KDIM 1024
#define TEMP_INV 20.0f
#define BK 64

typedef __bf16 bf16x8 __attribute__((ext_vector_type(8)));
typedef float f32x16 __attribute__((ext_vector_type(16)));

typedef __attribute__((address_space(3))) void lds_void_t;
typedef __attribute__((address_space(1))) void glb_void_t;

__device__ __forceinline__ void async_copy16(const void* g, void* l) {
    __builtin_amdgcn_global_load_lds((glb_void_t*)(uintptr_t)g,
                                     (lds_void_t*)(uint32_t)(uintptr_t)l,
                                     16, 0, 0);
}

__device__ __forceinline__ unsigned short f32_to_bf16_rne(float f) {
    union { float f; uint32_t u; } v;
    v.f = f;
    uint32_t u = v.u;
    return (unsigned short)((u + 0x7FFFu + ((u >> 16) & 1u)) >> 16);
}

// Wave-per-row prep: no LDS, no __syncthreads. Block = 4 waves = 4 rows.
__global__ __launch_bounds__(256) void prep_kernel(const float* __restrict__ x,
                                                   const float* __restrict__ y,
                                                   unsigned short* __restrict__ xb,
                                                   unsigned short* __restrict__ yb,
                                                   float* __restrict__ rnx,
                                                   float* __restrict__ rny) {
    const int wv = threadIdx.x >> 6;
    const int lane = threadIdx.x & 63;
    const int row = blockIdx.x * 4 + wv;
    const float* src = blockIdx.y ? y : x;
    unsigned short* dst = blockIdx.y ? yb : xb;
    float* rn = blockIdx.y ? rny : rnx;

    const float4* s4 = (const float4*)(src + (size_t)row * KDIM);
    ushort4* d4 = (ushort4*)(dst + (size_t)row * KDIM);

    float ss = 0.0f;
#pragma unroll
    for (int it = 0; it < 4; ++it) {
        float4 v = s4[lane + it * 64];
        ss += v.x * v.x + v.y * v.y + v.z * v.z + v.w * v.w;
        ushort4 b;
        b.x = f32_to_bf16_rne(v.x);
        b.y = f32_to_bf16_rne(v.y);
        b.z = f32_to_bf16_rne(v.z);
        b.w = f32_to_bf16_rne(v.w);
        d4[lane + it * 64] = b;
    }
#pragma unroll
    for (int off = 32; off > 0; off >>= 1) ss += __shfl_down(ss, off);
    if (lane == 0) rn[row] = 1.0f / fmaxf(sqrtf(ss), 1e-8f);
}

// 128x128 tile, BK=64, mfma_f32_32x32x16_bf16, 4 waves each 64x64 (2x2 of 32x32).
// LDS rows are 128 B (8 chunks of 16 B); chunk slot c' holds global chunk
// c' ^ (row&7) — XOR swizzle spreads reads over all 8 bank groups while the
// global_load_lds DMA stays lane-contiguous (we permute WHICH chunk a thread
// fetches, never where it writes).
__global__ __launch_bounds__(256, 4) void gemm_cos_kernel(const unsigned short* __restrict__ Xb,
                                                          const unsigned short* __restrict__ Yb,
                                                          const float* __restrict__ rnx,
                                                          const float* __restrict__ rny,
                                                          float* __restrict__ out) {
    __shared__ __bf16 As[128 * BK];  // 16 KB
    __shared__ __bf16 Bs[128 * BK];  // 16 KB

    const int tid = threadIdx.x;
    const int bm = blockIdx.y;
    const int bn = blockIdx.x;

    // Staging: thread t covers segment-row (t>>3), chunk slot (t&7); the global
    // chunk it must fetch is (t&7) ^ ((t>>3)&7). Each of 4 segments covers 32 rows.
    const int srow = tid >> 3;
    const int gchunk = (tid & 7) ^ (srow & 7);
    const unsigned short* gA = Xb + (size_t)(bm * 128 + srow) * KDIM + gchunk * 8;
    const unsigned short* gB = Yb + (size_t)(bn * 128 + srow) * KDIM + gchunk * 8;
    __bf16* lA = As + tid * 8;
    __bf16* lB = Bs + tid * 8;

    const int lane = tid & 63;
    const int wv = tid >> 6;
    const int wr = (wv >> 1) * 64;
    const int wc = (wv & 1) * 64;
    const int n32 = lane & 31;
    const int half = lane >> 5;
    const int rsw = n32 & 7;  // row-dependent part of the swizzle (wr, i*32 are mult of 8)

    // Element base offsets for the two row-tiles / col-tiles (row*64 elems per row).
    const int aOff0 = (wr + n32) * BK;
    const int aOff1 = (wr + 32 + n32) * BK;
    const int bOff0 = (wc + n32) * BK;
    const int bOff1 = (wc + 32 + n32) * BK;

    f32x16 acc00 = {}, acc01 = {}, acc10 = {}, acc11 = {};

    for (int kt = 0; kt < KDIM; kt += BK) {
        __syncthreads();
#pragma unroll
        for (int seg = 0; seg < 4; ++seg) {
            async_copy16(gA + kt + (size_t)seg * 32 * KDIM, lA + seg * 2048);
            async_copy16(gB + kt + (size_t)seg * 32 * KDIM, lB + seg * 2048);
        }
        __syncthreads();

#pragma unroll
        for (int s = 0; s < 4; ++s) {
            const int cp = ((2 * s + half) ^ rsw) * 8;  // swizzled chunk -> element offset
            bf16x8 a0 = *(const bf16x8*)(As + aOff0 + cp);
            bf16x8 a1 = *(const bf16x8*)(As + aOff1 + cp);
            bf16x8 b0 = *(const bf16x8*)(Bs + bOff0 + cp);
            bf16x8 b1 = *(const bf16x8*)(Bs + bOff1 + cp);
            acc00 = __builtin_amdgcn_mfma_f32_32x32x16_bf16(a0, b0, acc00, 0, 0, 0);
            acc01 = __builtin_amdgcn_mfma_f32_32x32x16_bf16(a0, b1, acc01, 0, 0, 0);
            acc10 = __builtin_amdgcn_mfma_f32_32x32x16_bf16(a1, b0, acc10, 0, 0, 0);
            acc11 = __builtin_amdgcn_mfma_f32_32x32x16_bf16(a1, b1, acc11, 0, 0, 0);
        }
    }

    // C/D layout (measured m74/m101): col = lane&31, row = (reg&3) + 8*(reg>>2) + 4*(lane>>5).
    const int grb = bm * 128 + wr + 4 * half;
    const int gcb = bn * 128 + wc + n32;
    const float sy0 = rny[gcb] * TEMP_INV;
    const float sy1 = rny[gcb + 32] * TEMP_INV;

#pragma unroll
    for (int r = 0; r < 16; ++r) {
        const int ro = (r & 3) + 8 * (r >> 2);
        {
            const int grow = grb + ro;
            const float rx = rnx[grow];
            out[(size_t)grow * NDIM + gcb] = acc00[r] * rx * sy0;
            out[(size_t)grow * NDIM + gcb + 32] = acc01[r] * rx * sy1;
        }
        {
            const int grow = grb + 32 + ro;
            const float rx = rnx[grow];
            out[(size_t)grow * NDIM + gcb] = acc10[r] * rx * sy0;
            out[(size_t)grow * NDIM + gcb + 32] = acc11[r] * rx * sy1;
        }
    }
}

extern "C" void kernel_launch(void* const* d_in, const int* in_sizes, int n_in,
                              void* d_out, int out_size, void* d_ws, size_t ws_size,
                              hipStream_t stream) {
    const float* x = (const float*)d_in[0];
    const float* y = (const float*)d_in[1];
    float* out = (float*)d_out;

    char* ws = (char*)d_ws;
    unsigned short* Xb = (unsigned short*)ws;                              // 8 MB
    unsigned short* Yb = (unsigned short*)(ws + (size_t)MDIM * KDIM * 2);  // 8 MB
    float* rnx = (float*)(ws + (size_t)(MDIM + NDIM) * KDIM * 2);
    float* rny = rnx + MDIM;

    prep_kernel<<<dim3(MDIM / 4, 2), 256, 0, stream>>>(x, y, Xb, Yb, rnx, rny);
    gemm_cos_kernel<<<dim3(NDIM / 128, MDIM / 128), 256, 0, stream>>>(Xb, Yb, rnx, rny, out);
}